// Round 11
// baseline (1757.692 us; speedup 1.0000x reference)
//
#include <hip/hip_runtime.h>
#include <hip/hip_bf16.h>

#define D_DIM 512
#define S_LEN 12
#define H_NUM 8
#define WMAT 262144       // 512*512

// ---- kernel1: G_B=4, 48 rows, 12 waves, 4-head groups, A-reuse s=4 ----
#define G_B1 4
#define ROWS1 48          // 3 M-tiles
#define THREADS1 768      // 12 waves: wave = (mat, head-in-group)
#define X_OFF   0         // [48][512] bf16 = 49152
#define QKV_OFF 49152     // 12 x [48][64] u16 (mat*4+head), 6144 B each = 73728
#define TBLK    3072      // 48*64 u16 elements per tensor
#define P_OFF   122880    // 16 x [12][20] f32 = 15360
#define SMEM1   138240    // 1 block/CU, 12 waves

// ---- kernel2 (R7-proven): G_B=4, 512 threads, 2 blocks/CU ----
#define G_B2 4
#define ROWS2 48
#define THREADS2 512
#define AST_OFF 0         // [48][512] bf16 = 49152
#define RED_OFF 49152     // [48][17] f32 = 3264
#define MU_OFF  52416     // [48][2] f32 = 384
#define SMEM2   52800     // x2 -> 2 blocks/CU

typedef __attribute__((ext_vector_type(8))) short bf16x8;
typedef __attribute__((ext_vector_type(4))) float f32x4;

__device__ __forceinline__ unsigned short f2bf(float f) {
    union { float f; unsigned u; } c; c.f = f;
    unsigned r = c.u + 0x7fffu + ((c.u >> 16) & 1u);
    return (unsigned short)(r >> 16);
}
__device__ __forceinline__ float bf2f(unsigned short u) {
    union { unsigned u; float f; } c; c.u = ((unsigned)u) << 16;
    return c.f;
}
// 16B-granule XOR swizzle, 512-col tiles
__device__ __forceinline__ int xswc(int row, int col) {
    return row * 512 + (((col >> 3) ^ (row & 7)) << 3) + (col & 7);
}
// 64-col tiles, stride 64, 16B-chunk XOR (full 8-chunk permutation)
__device__ __forceinline__ int qsw64(int row, int col) {
    return row * 64 + (((col >> 3) ^ (row & 7)) << 3) + (col & 7);
}

__global__ void prep_weights(const float* __restrict__ Wq, const float* __restrict__ Wk,
                             const float* __restrict__ Wv, const float* __restrict__ Wo,
                             unsigned short* __restrict__ wt) {
    int idx = blockIdx.x * 256 + threadIdx.x;   // 0 .. 4*WMAT-1
    int mat = idx >> 18;
    int rem = idx & (WMAT - 1);
    int e = rem >> 9, d = rem & 511;
    const float* W = (mat == 0) ? Wq : (mat == 1) ? Wk : (mat == 2) ? Wv : Wo;
    wt[idx] = f2bf(W[d * D_DIM + e]);           // wt[mat][e][d] = W[d][e]
}

// ---------------- kernel 1: QKV + attention -> A (f32, into d_out) ----------------
__global__ __launch_bounds__(THREADS1, 3) void qkv_attn(
    const float* __restrict__ x, const unsigned short* __restrict__ wt,
    const float* __restrict__ bq, const float* __restrict__ bk, const float* __restrict__ bv,
    const float* __restrict__ adj, float* __restrict__ aout)
{
    extern __shared__ char smem[];
    unsigned short* Xh  = (unsigned short*)(smem + X_OFF);
    unsigned short* QKV = (unsigned short*)(smem + QKV_OFF);  // 12 tensors of TBLK
    float* Pl = (float*)(smem + P_OFF);         // [16][12][20]

    const int tid  = threadIdx.x;
    const int lane = tid & 63;
    const int w    = tid >> 6;          // wave 0..11
    const int lr   = lane & 15;
    const int lg   = lane >> 4;
    const int lr12 = (lr < 12) ? lr : 11;       // true clamp
    const size_t row0 = (size_t)blockIdx.x * ROWS1;

    // stage X -> LDS bf16 (swizzled): 6144 chunks, 8/thread
    #pragma unroll
    for (int it = 0; it < 8; ++it) {
        int idx = it * THREADS1 + tid;
        int r = idx >> 7, col = (idx & 127) << 2;
        float4 v = *(const float4*)(x + (row0 + r) * (size_t)D_DIM + col);
        ushort4 pk;
        pk.x = f2bf(v.x); pk.y = f2bf(v.y); pk.z = f2bf(v.z); pk.w = f2bf(v.w);
        *(ushort4*)(Xh + xswc(r, col)) = pk;
    }
    __syncthreads();

    // wave task: mat = w>>2 (0=Q,1=K,2=V), head-in-group hh = w&3; full 64 cols of that head
    const int mat = w >> 2;
    const int hh  = w & 3;
    const float* bsel = (mat == 0) ? bq : (mat == 1) ? bk : bv;
    unsigned short* Tw = QKV + (mat * 4 + hh) * TBLK;

    #pragma unroll 1
    for (int hg = 0; hg < 2; ++hg) {
        const int hglob = hg * 4 + hh;
        // ---------------- QKV projection: wave's head, 4 col-tiles, 3 M-tiles ----------------
        f32x4 acc[3][4];                // [mt][nt]
        #pragma unroll
        for (int mt = 0; mt < 3; ++mt)
            #pragma unroll
            for (int nt = 0; nt < 4; ++nt) acc[mt][nt] = (f32x4){0.f, 0.f, 0.f, 0.f};

        const unsigned short* bp[4];
        bf16x8 bc[4];
        #pragma unroll
        for (int nt = 0; nt < 4; ++nt) {
            bp[nt] = wt + (size_t)mat * WMAT + (hglob * 64 + nt * 16 + lr) * D_DIM + lg * 8;
            bc[nt] = *(const bf16x8*)bp[nt];    // preload ks=0
        }
        #pragma unroll
        for (int ks = 0; ks < 16; ++ks) {
            bf16x8 bn[4];
            if (ks < 15) {
                #pragma unroll
                for (int nt = 0; nt < 4; ++nt)
                    bn[nt] = *(const bf16x8*)(bp[nt] + (ks + 1) * 32);
            }
            bf16x8 af[3];
            #pragma unroll
            for (int mt = 0; mt < 3; ++mt)
                af[mt] = *(const bf16x8*)(Xh + xswc(mt * 16 + lr, ks * 32 + lg * 8));
            #pragma unroll
            for (int nt = 0; nt < 4; ++nt)
                #pragma unroll
                for (int mt = 0; mt < 3; ++mt)
                    acc[mt][nt] = __builtin_amdgcn_mfma_f32_16x16x32_bf16(af[mt], bc[nt], acc[mt][nt], 0, 0, 0);
            if (ks < 15) {
                #pragma unroll
                for (int nt = 0; nt < 4; ++nt) bc[nt] = bn[nt];
            }
        }
        // store wave's head tensor (+bias)
        #pragma unroll
        for (int nt = 0; nt < 4; ++nt) {
            float bias = bsel[hglob * 64 + nt * 16 + lr];
            #pragma unroll
            for (int mt = 0; mt < 3; ++mt)
                #pragma unroll
                for (int j = 0; j < 4; ++j)
                    Tw[qsw64(mt * 16 + lg * 4 + j, nt * 16 + lr)] = f2bf(acc[mt][nt][j] + bias);
        }
        __syncthreads();   // all Q/K/V of this head-group visible

        // ---------------- attention: 16 tasks (item, head) over 12 waves ----------------
        for (int t = w; t < 16; t += 12) {
            const int ab = t & 3;               // batch item
            const int th = t >> 2;              // head-in-group
            const int h  = hg * 4 + th;
            const int rbA = ab * S_LEN;
            const unsigned short* Qb = QKV + (0 * 4 + th) * TBLK;
            const unsigned short* Kb = QKV + (1 * 4 + th) * TBLK;
            const unsigned short* Vb = QKV + (2 * 4 + th) * TBLK;

            f32x4 sacc = (f32x4){0.f, 0.f, 0.f, 0.f};
            #pragma unroll
            for (int k2 = 0; k2 < 2; ++k2) {
                bf16x8 ak = *(const bf16x8*)(Kb + qsw64(rbA + lr12, k2 * 32 + lg * 8));
                bf16x8 aq = *(const bf16x8*)(Qb + qsw64(rbA + lr12, k2 * 32 + lg * 8));
                sacc = __builtin_amdgcn_mfma_f32_16x16x32_bf16(ak, aq, sacc, 0, 0, 0);
            }
            float ab4[4] = {0.f, 0.f, 0.f, 0.f};
            if (lg < 3 && lr < 12) {
                float4 t4 = *(const float4*)(adj + (h * S_LEN + lr) * S_LEN + lg * 4);
                ab4[0] = t4.x; ab4[1] = t4.y; ab4[2] = t4.z; ab4[3] = t4.w;
            }
            float sc[4], e4[4];
            float m = -1e30f;
            #pragma unroll
            for (int j = 0; j < 4; ++j) {
                int tt = lg * 4 + j;
                sc[j] = (tt < 12) ? (sacc[j] * 0.125f + ab4[j]) : -1e30f;
                m = fmaxf(m, sc[j]);
            }
            m = fmaxf(m, __shfl_xor(m, 16));
            m = fmaxf(m, __shfl_xor(m, 32));
            float ssum = 0.f;
            #pragma unroll
            for (int j = 0; j < 4; ++j) { e4[j] = __expf(sc[j] - m); ssum += e4[j]; }
            ssum += __shfl_xor(ssum, 16);
            ssum += __shfl_xor(ssum, 32);
            float inv = 1.f / ssum;
            float* Pw = Pl + t * 240;
            if (lr < 12 && lg < 3) {
                f32x4 pvec = (f32x4){e4[0] * inv, e4[1] * inv, e4[2] * inv, e4[3] * inv};
                *(f32x4*)(Pw + lr * 20 + lg * 4) = pvec;
            }
            // same-wave P write -> read: no barrier needed (validated R5-R10)
            float vv[12];
            #pragma unroll
            for (int t2 = 0; t2 < 12; ++t2) vv[t2] = bf2f(Vb[qsw64(rbA + t2, lane)]);
            #pragma unroll
            for (int ss = 0; ss < 12; ++ss) {
                f32x4 pa = *(const f32x4*)(Pw + ss * 20);
                f32x4 pb = *(const f32x4*)(Pw + ss * 20 + 4);
                f32x4 pc = *(const f32x4*)(Pw + ss * 20 + 8);
                float o = 0.f;
                #pragma unroll
                for (int t2 = 0; t2 < 4; ++t2) o += pa[t2] * vv[t2];
                #pragma unroll
                for (int t2 = 0; t2 < 4; ++t2) o += pb[t2] * vv[4 + t2];
                #pragma unroll
                for (int t2 = 0; t2 < 4; ++t2) o += pc[t2] * vv[8 + t2];
                aout[(row0 + rbA + ss) * (size_t)D_DIM + h * 64 + lane] = o;
            }
        }
        if (hg == 0) __syncthreads();   // attention reads done before next group's stores
    }
}

// ---------------- kernel 2: out-proj + bias + residual + LayerNorm (in-place, R7-proven) ----------------
__global__ __launch_bounds__(THREADS2, 2) void oproj_ln(
    const float* __restrict__ x, const unsigned short* __restrict__ wt,
    const float* __restrict__ bo, const float* __restrict__ gamma,
    const float* __restrict__ beta, float* __restrict__ out)
{
    extern __shared__ char smem[];
    unsigned short* Ast = (unsigned short*)(smem + AST_OFF);  // [48][512] bf16
    float* red   = (float*)(smem + RED_OFF);   // [48][17]
    float* musig = (float*)(smem + MU_OFF);    // [48][2]

    const int tid  = threadIdx.x;
    const int lane = tid & 63;
    const int w    = tid >> 6;
    const int lr   = lane & 15;
    const int lg   = lane >> 4;
    const size_t row0 = (size_t)blockIdx.x * ROWS2;

    // stage A (f32 in out) -> LDS bf16 (swizzled); in-place safe (row-partitioned)
    #pragma unroll
    for (int it = 0; it < 12; ++it) {
        int idx = it * THREADS2 + tid;
        int r = idx >> 7, col = (idx & 127) << 2;
        float4 v = *(const float4*)(out + (row0 + r) * (size_t)D_DIM + col);
        ushort4 pk;
        pk.x = f2bf(v.x); pk.y = f2bf(v.y); pk.z = f2bf(v.z); pk.w = f2bf(v.w);
        *(ushort4*)(Ast + xswc(r, col)) = pk;
    }
    __syncthreads();

    f32x4 Y[3][4];
    #pragma unroll
    for (int mt = 0; mt < 3; ++mt)
        #pragma unroll
        for (int nt = 0; nt < 4; ++nt) Y[mt][nt] = (f32x4){0.f, 0.f, 0.f, 0.f};

    const unsigned short* obase = wt + (size_t)3 * WMAT + (w * 64 + lr) * D_DIM;
    #pragma unroll 2
    for (int ks = 0; ks < 16; ++ks) {
        bf16x8 afr[3];
        #pragma unroll
        for (int mt = 0; mt < 3; ++mt)
            afr[mt] = *(const bf16x8*)(Ast + xswc(mt * 16 + lr, ks * 32 + lg * 8));
        #pragma unroll
        for (int nt = 0; nt < 4; ++nt) {
            bf16x8 bfr = *(const bf16x8*)(obase + nt * 16 * D_DIM + ks * 32 + lg * 8);
            #pragma unroll
            for (int mt = 0; mt < 3; ++mt)
                Y[mt][nt] = __builtin_amdgcn_mfma_f32_16x16x32_bf16(afr[mt], bfr, Y[mt][nt], 0, 0, 0);
        }
    }

    // epilogue: +bo, +x (fp32), LayerNorm, store
    float bo4[4], gm4[4], bt4[4];
    int cols[4];
    #pragma unroll
    for (int nt = 0; nt < 4; ++nt) {
        cols[nt] = w * 64 + nt * 16 + lr;
        bo4[nt] = bo[cols[nt]]; gm4[nt] = gamma[cols[nt]]; bt4[nt] = beta[cols[nt]];
    }
    #pragma unroll
    for (int mt = 0; mt < 3; ++mt)
        #pragma unroll
        for (int j = 0; j < 4; ++j) {
            int rowl = mt * 16 + lg * 4 + j;
            const float* xrow = x + (row0 + rowl) * (size_t)D_DIM;
            float ps = 0.f, pq = 0.f;
            #pragma unroll
            for (int nt = 0; nt < 4; ++nt) {
                float y = Y[mt][nt][j] + bo4[nt] + xrow[cols[nt]];
                Y[mt][nt][j] = y;
                ps += y; pq += y * y;
            }
            ps += __shfl_xor(ps, 1); pq += __shfl_xor(pq, 1);
            ps += __shfl_xor(ps, 2); pq += __shfl_xor(pq, 2);
            ps += __shfl_xor(ps, 4); pq += __shfl_xor(pq, 4);
            ps += __shfl_xor(ps, 8); pq += __shfl_xor(pq, 8);
            if (lr == 0) { red[rowl * 17 + w * 2] = ps; red[rowl * 17 + w * 2 + 1] = pq; }
        }
    __syncthreads();
    if (tid < ROWS2) {
        float s = 0.f, q = 0.f;
        #pragma unroll
        for (int w8 = 0; w8 < 8; ++w8) { s += red[tid * 17 + w8 * 2]; q += red[tid * 17 + w8 * 2 + 1]; }
        float mu = s * (1.f / 512.f);
        float var = q * (1.f / 512.f) - mu * mu;
        musig[tid * 2] = mu;
        musig[tid * 2 + 1] = rsqrtf(var + 1e-5f);
    }
    __syncthreads();
    #pragma unroll
    for (int mt = 0; mt < 3; ++mt)
        #pragma unroll
        for (int j = 0; j < 4; ++j) {
            int rowl = mt * 16 + lg * 4 + j;
            float mu = musig[rowl * 2], rs = musig[rowl * 2 + 1];
            float* orow = out + (row0 + rowl) * (size_t)D_DIM;
            #pragma unroll
            for (int nt = 0; nt < 4; ++nt)
                orow[cols[nt]] = (Y[mt][nt][j] - mu) * rs * gm4[nt] + bt4[nt];
        }
}

extern "C" void kernel_launch(void* const* d_in, const int* in_sizes, int n_in,
                              void* d_out, int out_size, void* d_ws, size_t ws_size,
                              hipStream_t stream) {
    (void)in_sizes; (void)n_in; (void)out_size; (void)ws_size;
    const float* x     = (const float*)d_in[0];
    const float* Wq    = (const float*)d_in[1];
    const float* bq    = (const float*)d_in[2];
    const float* Wk    = (const float*)d_in[3];
    const float* bk    = (const float*)d_in[4];
    const float* Wv    = (const float*)d_in[5];
    const float* bv    = (const float*)d_in[6];
    const float* adj   = (const float*)d_in[7];
    const float* Wo    = (const float*)d_in[8];
    const float* bo    = (const float*)d_in[9];
    const float* gamma = (const float*)d_in[10];
    const float* beta  = (const float*)d_in[11];
    unsigned short* wt = (unsigned short*)d_ws;      // 4 * 512*512 bf16 = 2 MiB
    float* outf = (float*)d_out;

    prep_weights<<<4096, 256, 0, stream>>>(Wq, Wk, Wv, Wo, wt);
    qkv_attn<<<16384 / G_B1, THREADS1, SMEM1, stream>>>(x, wt, bq, bk, bv, adj, outf);
    oproj_ln<<<16384 / G_B2, THREADS2, SMEM2, stream>>>(x, wt, bo, gamma, beta, outf);
}

// Round 12
// 1436.142 us; speedup vs baseline: 1.2239x; 1.2239x over previous
//
#include <hip/hip_runtime.h>
#include <hip/hip_bf16.h>

#define D_DIM 512
#define S_LEN 12
#define H_NUM 8
#define WMAT 262144       // 512*512

// ---- kernel1: G_B=4, 48 rows, 8 waves, 2-head groups, s=3 col-tiles/wave ----
#define G_B1 4
#define ROWS1 48          // 3 M-tiles of 16
#define THREADS1 512      // 8 waves
#define X_OFF   0         // [48][512] bf16 = 49152
#define QKV_OFF 49152     // 6 x [48][64] u16 (mat*2+head), 6144 B each = 36864
#define TBLK    3072      // 48*64 u16 elements per tensor
#define P_OFF   86016     // 8 x [12][20] f32 = 7680
#define SMEM1   93696     // 1 block/CU, 8 waves

// ---- kernel2 (R7-proven): G_B=4, 512 threads, 2 blocks/CU ----
#define G_B2 4
#define ROWS2 48
#define THREADS2 512
#define AST_OFF 0         // [48][512] bf16 = 49152
#define RED_OFF 49152     // [48][17] f32 = 3264
#define MU_OFF  52416     // [48][2] f32 = 384
#define SMEM2   52800     // x2 -> 2 blocks/CU

typedef __attribute__((ext_vector_type(8))) short bf16x8;
typedef __attribute__((ext_vector_type(4))) float f32x4;

__device__ __forceinline__ unsigned short f2bf(float f) {
    union { float f; unsigned u; } c; c.f = f;
    unsigned r = c.u + 0x7fffu + ((c.u >> 16) & 1u);
    return (unsigned short)(r >> 16);
}
__device__ __forceinline__ float bf2f(unsigned short u) {
    union { unsigned u; float f; } c; c.u = ((unsigned)u) << 16;
    return c.f;
}
// 16B-granule XOR swizzle, 512-col tiles
__device__ __forceinline__ int xswc(int row, int col) {
    return row * 512 + (((col >> 3) ^ (row & 7)) << 3) + (col & 7);
}
// 64-col tiles, stride 64, 16B-chunk XOR
__device__ __forceinline__ int qsw64(int row, int col) {
    return row * 64 + (((col >> 3) ^ (row & 7)) << 3) + (col & 7);
}

__global__ void prep_weights(const float* __restrict__ Wq, const float* __restrict__ Wk,
                             const float* __restrict__ Wv, const float* __restrict__ Wo,
                             unsigned short* __restrict__ wt) {
    int idx = blockIdx.x * 256 + threadIdx.x;   // 0 .. 4*WMAT-1
    int mat = idx >> 18;
    int rem = idx & (WMAT - 1);
    int e = rem >> 9, d = rem & 511;
    const float* W = (mat == 0) ? Wq : (mat == 1) ? Wk : (mat == 2) ? Wv : Wo;
    wt[idx] = f2bf(W[d * D_DIM + e]);           // wt[mat][e][d] = W[d][e]
}

// ---------------- kernel 1: QKV + attention -> A (f32, into d_out) ----------------
__global__ __launch_bounds__(THREADS1, 2) void qkv_attn(
    const float* __restrict__ x, const unsigned short* __restrict__ wt,
    const float* __restrict__ bq, const float* __restrict__ bk, const float* __restrict__ bv,
    const float* __restrict__ adj, float* __restrict__ aout)
{
    extern __shared__ char smem[];
    unsigned short* Xh  = (unsigned short*)(smem + X_OFF);
    unsigned short* QKV = (unsigned short*)(smem + QKV_OFF);  // 6 tensors of TBLK
    float* Pl = (float*)(smem + P_OFF);         // [8][12][20]

    const int tid  = threadIdx.x;
    const int lane = tid & 63;
    const int w    = tid >> 6;          // wave 0..7
    const int lr   = lane & 15;
    const int lg   = lane >> 4;
    const int lr12 = (lr < 12) ? lr : 11;       // true clamp
    const size_t row0 = (size_t)blockIdx.x * ROWS1;

    // stage X -> LDS bf16 (swizzled): 6144 chunks, 12/thread
    #pragma unroll
    for (int it = 0; it < 12; ++it) {
        int idx = it * THREADS1 + tid;
        int r = idx >> 7, col = (idx & 127) << 2;
        float4 v = *(const float4*)(x + (row0 + r) * (size_t)D_DIM + col);
        ushort4 pk;
        pk.x = f2bf(v.x); pk.y = f2bf(v.y); pk.z = f2bf(v.z); pk.w = f2bf(v.w);
        *(ushort4*)(Xh + xswc(r, col)) = pk;
    }
    __syncthreads();

    // wave tasks per 2-head group: col-space [mat(3)][head(2)][col(64)] = 384 cols,
    // wave w owns cols [48w, 48w+48) = 3 tiles of 16 (never straddle head or mat)
    int matn[3], hhn[3], c0n[3];
    #pragma unroll
    for (int ct = 0; ct < 3; ++ct) {
        int colglob = w * 48 + ct * 16;
        matn[ct] = colglob >> 7;        // 128 cols per mat per group
        int rem = colglob & 127;
        hhn[ct] = rem >> 6;
        c0n[ct] = rem & 63;
    }
    // attention task: 8 tasks = 4 items x 2 heads, one per wave
    const int ab = w & 3;               // batch item
    const int th = w >> 2;              // head-in-group
    const int rbA = ab * S_LEN;

    #pragma unroll 1
    for (int hg = 0; hg < 4; ++hg) {
        // ---------------- QKV projection for head-group hg (2 heads) ----------------
        f32x4 acc[3][3];                // [mt][ct]
        #pragma unroll
        for (int mt = 0; mt < 3; ++mt)
            #pragma unroll
            for (int ct = 0; ct < 3; ++ct) acc[mt][ct] = (f32x4){0.f, 0.f, 0.f, 0.f};

        const unsigned short* bp[3];
        #pragma unroll
        for (int ct = 0; ct < 3; ++ct)
            bp[ct] = wt + (size_t)matn[ct] * WMAT +
                     ((hg * 2 + hhn[ct]) * 64 + c0n[ct] + lr) * D_DIM + lg * 8;

        #pragma unroll
        for (int ks = 0; ks < 16; ++ks) {
            bf16x8 af[3];
            #pragma unroll
            for (int mt = 0; mt < 3; ++mt)
                af[mt] = *(const bf16x8*)(Xh + xswc(mt * 16 + lr, ks * 32 + lg * 8));
            #pragma unroll
            for (int ct = 0; ct < 3; ++ct) {
                bf16x8 bc = *(const bf16x8*)(bp[ct] + ks * 32);
                #pragma unroll
                for (int mt = 0; mt < 3; ++mt)
                    acc[mt][ct] = __builtin_amdgcn_mfma_f32_16x16x32_bf16(af[mt], bc, acc[mt][ct], 0, 0, 0);
            }
        }
        // store Q/K/V (+bias)
        #pragma unroll
        for (int ct = 0; ct < 3; ++ct) {
            int mat = matn[ct];
            unsigned short* T = QKV + (mat * 2 + hhn[ct]) * TBLK;
            const float* bsel = (mat == 0) ? bq : (mat == 1) ? bk : bv;
            float bias = bsel[(hg * 2 + hhn[ct]) * 64 + c0n[ct] + lr];
            #pragma unroll
            for (int mt = 0; mt < 3; ++mt)
                #pragma unroll
                for (int j = 0; j < 4; ++j)
                    T[qsw64(mt * 16 + lg * 4 + j, c0n[ct] + lr)] = f2bf(acc[mt][ct][j] + bias);
        }
        __syncthreads();   // Q/K/V of this head-group visible

        // ---------------- attention: wave = (item ab, head hg*2+th) ----------------
        {
            const int h = hg * 2 + th;
            const unsigned short* Qb = QKV + (0 * 2 + th) * TBLK;
            const unsigned short* Kb = QKV + (1 * 2 + th) * TBLK;
            const unsigned short* Vb = QKV + (2 * 2 + th) * TBLK;

            f32x4 sacc = (f32x4){0.f, 0.f, 0.f, 0.f};
            #pragma unroll
            for (int k2 = 0; k2 < 2; ++k2) {
                bf16x8 ak = *(const bf16x8*)(Kb + qsw64(rbA + lr12, k2 * 32 + lg * 8));
                bf16x8 aq = *(const bf16x8*)(Qb + qsw64(rbA + lr12, k2 * 32 + lg * 8));
                sacc = __builtin_amdgcn_mfma_f32_16x16x32_bf16(ak, aq, sacc, 0, 0, 0);
            }
            float ab4[4] = {0.f, 0.f, 0.f, 0.f};
            if (lg < 3 && lr < 12) {
                float4 t4 = *(const float4*)(adj + (h * S_LEN + lr) * S_LEN + lg * 4);
                ab4[0] = t4.x; ab4[1] = t4.y; ab4[2] = t4.z; ab4[3] = t4.w;
            }
            float sc[4], e4[4];
            float m = -1e30f;
            #pragma unroll
            for (int j = 0; j < 4; ++j) {
                int tt = lg * 4 + j;
                sc[j] = (tt < 12) ? (sacc[j] * 0.125f + ab4[j]) : -1e30f;
                m = fmaxf(m, sc[j]);
            }
            m = fmaxf(m, __shfl_xor(m, 16));
            m = fmaxf(m, __shfl_xor(m, 32));
            float ssum = 0.f;
            #pragma unroll
            for (int j = 0; j < 4; ++j) { e4[j] = __expf(sc[j] - m); ssum += e4[j]; }
            ssum += __shfl_xor(ssum, 16);
            ssum += __shfl_xor(ssum, 32);
            float inv = 1.f / ssum;
            float* Pw = Pl + w * 240;
            if (lr < 12 && lg < 3) {
                f32x4 pvec = (f32x4){e4[0] * inv, e4[1] * inv, e4[2] * inv, e4[3] * inv};
                *(f32x4*)(Pw + lr * 20 + lg * 4) = pvec;
            }
            // same-wave P write -> read: no barrier needed (validated R5-R11)
            float vv[12];
            #pragma unroll
            for (int t2 = 0; t2 < 12; ++t2) vv[t2] = bf2f(Vb[qsw64(rbA + t2, lane)]);
            #pragma unroll
            for (int ss = 0; ss < 12; ++ss) {
                f32x4 pa = *(const f32x4*)(Pw + ss * 20);
                f32x4 pb = *(const f32x4*)(Pw + ss * 20 + 4);
                f32x4 pc = *(const f32x4*)(Pw + ss * 20 + 8);
                float o = 0.f;
                #pragma unroll
                for (int t2 = 0; t2 < 4; ++t2) o += pa[t2] * vv[t2];
                #pragma unroll
                for (int t2 = 0; t2 < 4; ++t2) o += pb[t2] * vv[4 + t2];
                #pragma unroll
                for (int t2 = 0; t2 < 4; ++t2) o += pc[t2] * vv[8 + t2];
                aout[(row0 + rbA + ss) * (size_t)D_DIM + h * 64 + lane] = o;
            }
        }
        if (hg < 3) __syncthreads();    // attention reads done before next group's stores
    }
}

// ---------------- kernel 2: out-proj + bias + residual + LayerNorm (in-place, R7-proven) ----------------
__global__ __launch_bounds__(THREADS2, 2) void oproj_ln(
    const float* __restrict__ x, const unsigned short* __restrict__ wt,
    const float* __restrict__ bo, const float* __restrict__ gamma,
    const float* __restrict__ beta, float* __restrict__ out)
{
    extern __shared__ char smem[];
    unsigned short* Ast = (unsigned short*)(smem + AST_OFF);  // [48][512] bf16
    float* red   = (float*)(smem + RED_OFF);   // [48][17]
    float* musig = (float*)(smem + MU_OFF);    // [48][2]

    const int tid  = threadIdx.x;
    const int lane = tid & 63;
    const int w    = tid >> 6;
    const int lr   = lane & 15;
    const int lg   = lane >> 4;
    const size_t row0 = (size_t)blockIdx.x * ROWS2;

    // stage A (f32 in out) -> LDS bf16 (swizzled); in-place safe (row-partitioned)
    #pragma unroll
    for (int it = 0; it < 12; ++it) {
        int idx = it * THREADS2 + tid;
        int r = idx >> 7, col = (idx & 127) << 2;
        float4 v = *(const float4*)(out + (row0 + r) * (size_t)D_DIM + col);
        ushort4 pk;
        pk.x = f2bf(v.x); pk.y = f2bf(v.y); pk.z = f2bf(v.z); pk.w = f2bf(v.w);
        *(ushort4*)(Ast + xswc(r, col)) = pk;
    }
    __syncthreads();

    f32x4 Y[3][4];
    #pragma unroll
    for (int mt = 0; mt < 3; ++mt)
        #pragma unroll
        for (int nt = 0; nt < 4; ++nt) Y[mt][nt] = (f32x4){0.f, 0.f, 0.f, 0.f};

    const unsigned short* obase = wt + (size_t)3 * WMAT + (w * 64 + lr) * D_DIM;
    #pragma unroll 2
    for (int ks = 0; ks < 16; ++ks) {
        bf16x8 afr[3];
        #pragma unroll
        for (int mt = 0; mt < 3; ++mt)
            afr[mt] = *(const bf16x8*)(Ast + xswc(mt * 16 + lr, ks * 32 + lg * 8));
        #pragma unroll
        for (int nt = 0; nt < 4; ++nt) {
            bf16x8 bfr = *(const bf16x8*)(obase + nt * 16 * D_DIM + ks * 32 + lg * 8);
            #pragma unroll
            for (int mt = 0; mt < 3; ++mt)
                Y[mt][nt] = __builtin_amdgcn_mfma_f32_16x16x32_bf16(afr[mt], bfr, Y[mt][nt], 0, 0, 0);
        }
    }

    // epilogue: +bo, +x (fp32), LayerNorm, store
    float bo4[4], gm4[4], bt4[4];
    int cols[4];
    #pragma unroll
    for (int nt = 0; nt < 4; ++nt) {
        cols[nt] = w * 64 + nt * 16 + lr;
        bo4[nt] = bo[cols[nt]]; gm4[nt] = gamma[cols[nt]]; bt4[nt] = beta[cols[nt]];
    }
    #pragma unroll
    for (int mt = 0; mt < 3; ++mt)
        #pragma unroll
        for (int j = 0; j < 4; ++j) {
            int rowl = mt * 16 + lg * 4 + j;
            const float* xrow = x + (row0 + rowl) * (size_t)D_DIM;
            float ps = 0.f, pq = 0.f;
            #pragma unroll
            for (int nt = 0; nt < 4; ++nt) {
                float y = Y[mt][nt][j] + bo4[nt] + xrow[cols[nt]];
                Y[mt][nt][j] = y;
                ps += y; pq += y * y;
            }
            ps += __shfl_xor(ps, 1); pq += __shfl_xor(pq, 1);
            ps += __shfl_xor(ps, 2); pq += __shfl_xor(pq, 2);
            ps += __shfl_xor(ps, 4); pq += __shfl_xor(pq, 4);
            ps += __shfl_xor(ps, 8); pq += __shfl_xor(pq, 8);
            if (lr == 0) { red[rowl * 17 + w * 2] = ps; red[rowl * 17 + w * 2 + 1] = pq; }
        }
    __syncthreads();
    if (tid < ROWS2) {
        float s = 0.f, q = 0.f;
        #pragma unroll
        for (int w8 = 0; w8 < 8; ++w8) { s += red[tid * 17 + w8 * 2]; q += red[tid * 17 + w8 * 2 + 1]; }
        float mu = s * (1.f / 512.f);
        float var = q * (1.f / 512.f) - mu * mu;
        musig[tid * 2] = mu;
        musig[tid * 2 + 1] = rsqrtf(var + 1e-5f);
    }
    __syncthreads();
    #pragma unroll
    for (int mt = 0; mt < 3; ++mt)
        #pragma unroll
        for (int j = 0; j < 4; ++j) {
            int rowl = mt * 16 + lg * 4 + j;
            float mu = musig[rowl * 2], rs = musig[rowl * 2 + 1];
            float* orow = out + (row0 + rowl) * (size_t)D_DIM;
            #pragma unroll
            for (int nt = 0; nt < 4; ++nt)
                orow[cols[nt]] = (Y[mt][nt][j] - mu) * rs * gm4[nt] + bt4[nt];
        }
}

extern "C" void kernel_launch(void* const* d_in, const int* in_sizes, int n_in,
                              void* d_out, int out_size, void* d_ws, size_t ws_size,
                              hipStream_t stream) {
    (void)in_sizes; (void)n_in; (void)out_size; (void)ws_size;
    const float* x     = (const float*)d_in[0];
    const float* Wq    = (const float*)d_in[1];
    const float* bq    = (const float*)d_in[2];
    const float* Wk    = (const float*)d_in[3];
    const float* bk    = (const float*)d_in[4];
    const float* Wv    = (const float*)d_in[5];
    const float* bv    = (const float*)d_in[6];
    const float* adj   = (const float*)d_in[7];
    const float* Wo    = (const float*)d_in[8];
    const float* bo    = (const float*)d_in[9];
    const float* gamma = (const float*)d_in[10];
    const float* beta  = (const float*)d_in[11];
    unsigned short* wt = (unsigned short*)d_ws;      // 4 * 512*512 bf16 = 2 MiB
    float* outf = (float*)d_out;

    prep_weights<<<4096, 256, 0, stream>>>(Wq, Wk, Wv, Wo, wt);
    qkv_attn<<<16384 / G_B1, THREADS1, SMEM1, stream>>>(x, wt, bq, bk, bv, adj, outf);
    oproj_ln<<<16384 / G_B2, THREADS2, SMEM2, stream>>>(x, wt, bo, gamma, beta, outf);
}

// Round 13
// 1387.924 us; speedup vs baseline: 1.2664x; 1.0347x over previous
//
#include <hip/hip_runtime.h>
#include <hip/hip_bf16.h>

#define D_DIM 512
#define S_LEN 12
#define H_NUM 8
#define WMAT 262144       // 512*512

// ---- kernel1: G_B=4, 48 rows, 12 waves, 2-head groups, 2 col-tiles/wave ----
#define G_B1 4
#define ROWS1 48          // 3 M-tiles of 16
#define THREADS1 768      // 12 waves
#define X_OFF   0         // [48][512] bf16 = 49152
#define QKV_OFF 49152     // 6 x [48][64] u16 (mat*2+head) = 36864
#define TBLK    3072      // 48*64 u16 per tensor
#define P_OFF   86016     // 8 x [12][20] f32 = 7680
#define SMEM1   93696     // 1 block/CU, 12 waves/CU

// ---- kernel2: G_B=4, 512 threads, 2 blocks/CU; A read as bf16 ----
#define G_B2 4
#define ROWS2 48
#define THREADS2 512
#define AST_OFF 0         // [48][512] bf16 = 49152
#define RED_OFF 49152     // [48][17] f32 = 3264
#define MU_OFF  52416     // [48][2] f32 = 384
#define SMEM2   52800     // x2 -> 2 blocks/CU

// A intermediate layout: bf16, row r at u16-elem index r*1024 + c
// (= low 1024 B of row r's 2048 B f32 slot in d_out -> K2 block reads exactly
//  the bytes it later overwrites: in-place, no cross-block overlap at all)

typedef __attribute__((ext_vector_type(8))) short bf16x8;
typedef __attribute__((ext_vector_type(4))) float f32x4;

__device__ __forceinline__ unsigned short f2bf(float f) {
    union { float f; unsigned u; } c; c.f = f;
    unsigned r = c.u + 0x7fffu + ((c.u >> 16) & 1u);
    return (unsigned short)(r >> 16);
}
__device__ __forceinline__ float bf2f(unsigned short u) {
    union { unsigned u; float f; } c; c.u = ((unsigned)u) << 16;
    return c.f;
}
// 16B-granule XOR swizzle, 512-col tiles
__device__ __forceinline__ int xswc(int row, int col) {
    return row * 512 + (((col >> 3) ^ (row & 7)) << 3) + (col & 7);
}
// 64-col tiles, stride 64, 16B-chunk XOR
__device__ __forceinline__ int qsw64(int row, int col) {
    return row * 64 + (((col >> 3) ^ (row & 7)) << 3) + (col & 7);
}

__global__ void prep_weights(const float* __restrict__ Wq, const float* __restrict__ Wk,
                             const float* __restrict__ Wv, const float* __restrict__ Wo,
                             unsigned short* __restrict__ wt) {
    int idx = blockIdx.x * 256 + threadIdx.x;   // 0 .. 4*WMAT-1
    int mat = idx >> 18;
    int rem = idx & (WMAT - 1);
    int e = rem >> 9, d = rem & 511;
    const float* W = (mat == 0) ? Wq : (mat == 1) ? Wk : (mat == 2) ? Wv : Wo;
    wt[idx] = f2bf(W[d * D_DIM + e]);           // wt[mat][e][d] = W[d][e]
}

// ---------------- kernel 1: QKV + attention -> A (bf16, packed into d_out) ----------------
__global__ __launch_bounds__(THREADS1, 3) void qkv_attn(
    const float* __restrict__ x, const unsigned short* __restrict__ wt,
    const float* __restrict__ bq, const float* __restrict__ bk, const float* __restrict__ bv,
    const float* __restrict__ adj, unsigned short* __restrict__ aout)
{
    extern __shared__ char smem[];
    unsigned short* Xh  = (unsigned short*)(smem + X_OFF);
    unsigned short* QKV = (unsigned short*)(smem + QKV_OFF);  // 6 tensors of TBLK
    float* Pl = (float*)(smem + P_OFF);         // [8][12][20]

    const int tid  = threadIdx.x;
    const int lane = tid & 63;
    const int w    = tid >> 6;          // wave 0..11
    const int lr   = lane & 15;
    const int lg   = lane >> 4;
    const int lr12 = (lr < 12) ? lr : 11;       // true clamp
    const size_t row0 = (size_t)blockIdx.x * ROWS1;

    // stage X -> LDS bf16 (swizzled): 6144 chunks of 4 f32, 8/thread
    #pragma unroll
    for (int it = 0; it < 8; ++it) {
        int idx = it * THREADS1 + tid;
        int r = idx >> 7, col = (idx & 127) << 2;
        float4 v = *(const float4*)(x + (row0 + r) * (size_t)D_DIM + col);
        ushort4 pk;
        pk.x = f2bf(v.x); pk.y = f2bf(v.y); pk.z = f2bf(v.z); pk.w = f2bf(v.w);
        *(ushort4*)(Xh + xswc(r, col)) = pk;
    }
    __syncthreads();

    // wave tasks per 2-head group: col-space [mat(3)][head(2)][col(64)] = 384 cols,
    // wave w owns 2 tiles of 16: cols [32w, 32w+32) (tiles never straddle head/mat)
    int matn[2], hhn[2], c0n[2];
    #pragma unroll
    for (int ct = 0; ct < 2; ++ct) {
        int colglob = w * 32 + ct * 16;
        matn[ct] = colglob >> 7;        // 128 cols per mat per group
        int rem = colglob & 127;
        hhn[ct] = rem >> 6;
        c0n[ct] = rem & 63;
    }
    // attention: 8 tasks = 4 items x 2 heads, waves 0-7
    const int ab = w & 3;               // batch item
    const int th = w >> 2;              // head-in-group
    const int rbA = ab * S_LEN;

    #pragma unroll 1
    for (int hg = 0; hg < 4; ++hg) {
        // ---------------- QKV projection for head-group hg (2 heads) ----------------
        f32x4 acc[3][2];                // [mt][ct]
        #pragma unroll
        for (int mt = 0; mt < 3; ++mt)
            #pragma unroll
            for (int ct = 0; ct < 2; ++ct) acc[mt][ct] = (f32x4){0.f, 0.f, 0.f, 0.f};

        const unsigned short* bp[2];
        #pragma unroll
        for (int ct = 0; ct < 2; ++ct)
            bp[ct] = wt + (size_t)matn[ct] * WMAT +
                     ((hg * 2 + hhn[ct]) * 64 + c0n[ct] + lr) * D_DIM + lg * 8;

        #pragma unroll
        for (int ks = 0; ks < 16; ++ks) {
            bf16x8 b0 = *(const bf16x8*)(bp[0] + ks * 32);
            bf16x8 b1 = *(const bf16x8*)(bp[1] + ks * 32);
            bf16x8 af[3];
            #pragma unroll
            for (int mt = 0; mt < 3; ++mt)
                af[mt] = *(const bf16x8*)(Xh + xswc(mt * 16 + lr, ks * 32 + lg * 8));
            #pragma unroll
            for (int mt = 0; mt < 3; ++mt) {
                acc[mt][0] = __builtin_amdgcn_mfma_f32_16x16x32_bf16(af[mt], b0, acc[mt][0], 0, 0, 0);
                acc[mt][1] = __builtin_amdgcn_mfma_f32_16x16x32_bf16(af[mt], b1, acc[mt][1], 0, 0, 0);
            }
        }
        // store Q/K/V (+bias)
        #pragma unroll
        for (int ct = 0; ct < 2; ++ct) {
            int mat = matn[ct];
            unsigned short* T = QKV + (mat * 2 + hhn[ct]) * TBLK;
            const float* bsel = (mat == 0) ? bq : (mat == 1) ? bk : bv;
            float bias = bsel[(hg * 2 + hhn[ct]) * 64 + c0n[ct] + lr];
            #pragma unroll
            for (int mt = 0; mt < 3; ++mt)
                #pragma unroll
                for (int j = 0; j < 4; ++j)
                    T[qsw64(mt * 16 + lg * 4 + j, c0n[ct] + lr)] = f2bf(acc[mt][ct][j] + bias);
        }
        __syncthreads();   // Q/K/V of this head-group visible

        // ---------------- attention: waves 0-7, task (item ab, head hg*2+th) ----------------
        if (w < 8) {
            const int h = hg * 2 + th;
            const unsigned short* Qb = QKV + (0 * 2 + th) * TBLK;
            const unsigned short* Kb = QKV + (1 * 2 + th) * TBLK;
            const unsigned short* Vb = QKV + (2 * 2 + th) * TBLK;

            f32x4 sacc = (f32x4){0.f, 0.f, 0.f, 0.f};
            #pragma unroll
            for (int k2 = 0; k2 < 2; ++k2) {
                bf16x8 ak = *(const bf16x8*)(Kb + qsw64(rbA + lr12, k2 * 32 + lg * 8));
                bf16x8 aq = *(const bf16x8*)(Qb + qsw64(rbA + lr12, k2 * 32 + lg * 8));
                sacc = __builtin_amdgcn_mfma_f32_16x16x32_bf16(ak, aq, sacc, 0, 0, 0);
            }
            float ab4[4] = {0.f, 0.f, 0.f, 0.f};
            if (lg < 3 && lr < 12) {
                float4 t4 = *(const float4*)(adj + (h * S_LEN + lr) * S_LEN + lg * 4);
                ab4[0] = t4.x; ab4[1] = t4.y; ab4[2] = t4.z; ab4[3] = t4.w;
            }
            float sc[4], e4[4];
            float m = -1e30f;
            #pragma unroll
            for (int j = 0; j < 4; ++j) {
                int tt = lg * 4 + j;
                sc[j] = (tt < 12) ? (sacc[j] * 0.125f + ab4[j]) : -1e30f;
                m = fmaxf(m, sc[j]);
            }
            m = fmaxf(m, __shfl_xor(m, 16));
            m = fmaxf(m, __shfl_xor(m, 32));
            float ssum = 0.f;
            #pragma unroll
            for (int j = 0; j < 4; ++j) { e4[j] = __expf(sc[j] - m); ssum += e4[j]; }
            ssum += __shfl_xor(ssum, 16);
            ssum += __shfl_xor(ssum, 32);
            float inv = 1.f / ssum;
            float* Pw = Pl + w * 240;
            if (lr < 12 && lg < 3) {
                f32x4 pvec = (f32x4){e4[0] * inv, e4[1] * inv, e4[2] * inv, e4[3] * inv};
                *(f32x4*)(Pw + lr * 20 + lg * 4) = pvec;
            }
            // same-wave P write -> read: no barrier needed (validated R5-R12)
            float vv[12];
            #pragma unroll
            for (int t2 = 0; t2 < 12; ++t2) vv[t2] = bf2f(Vb[qsw64(rbA + t2, lane)]);
            #pragma unroll
            for (int ss = 0; ss < 12; ++ss) {
                f32x4 pa = *(const f32x4*)(Pw + ss * 20);
                f32x4 pb = *(const f32x4*)(Pw + ss * 20 + 4);
                f32x4 pc = *(const f32x4*)(Pw + ss * 20 + 8);
                float o = 0.f;
                #pragma unroll
                for (int t2 = 0; t2 < 4; ++t2) o += pa[t2] * vv[t2];
                #pragma unroll
                for (int t2 = 0; t2 < 4; ++t2) o += pb[t2] * vv[4 + t2];
                #pragma unroll
                for (int t2 = 0; t2 < 4; ++t2) o += pc[t2] * vv[8 + t2];
                // bf16 A, packed: row r's data at u16-elem r*1024 + col
                aout[(row0 + rbA + ss) * 1024 + h * 64 + lane] = f2bf(o);
            }
        }
        if (hg < 3) __syncthreads();    // attention reads done before next group's stores
    }
}

// ---------------- kernel 2: out-proj + bias + residual + LayerNorm (in-place) ----------------
__global__ __launch_bounds__(THREADS2, 2) void oproj_ln(
    const float* __restrict__ x, const unsigned short* __restrict__ wt,
    const float* __restrict__ bo, const float* __restrict__ gamma,
    const float* __restrict__ beta, float* __restrict__ out)
{
    extern __shared__ char smem[];
    unsigned short* Ast = (unsigned short*)(smem + AST_OFF);  // [48][512] bf16
    float* red   = (float*)(smem + RED_OFF);   // [48][17]
    float* musig = (float*)(smem + MU_OFF);    // [48][2]

    const int tid  = threadIdx.x;
    const int lane = tid & 63;
    const int w    = tid >> 6;
    const int lr   = lane & 15;
    const int lg   = lane >> 4;
    const size_t row0 = (size_t)blockIdx.x * ROWS2;
    const unsigned short* abase = (const unsigned short*)out;  // bf16 A region

    // stage A (bf16, low half of each row's f32 slot) -> LDS, straight copy.
    // 3072 chunks of 8 u16 (16B), 6/thread. All reads precede the barrier; this
    // block's f32 writes cover exactly these bytes -> in-place safe.
    #pragma unroll
    for (int it = 0; it < 6; ++it) {
        int idx = it * THREADS2 + tid;
        int r = idx >> 6, c8 = (idx & 63) << 3;
        uint4 v = *(const uint4*)(abase + (row0 + r) * 1024 + c8);
        *(uint4*)(Ast + xswc(r, c8)) = v;
    }
    __syncthreads();

    f32x4 Y[3][4];
    #pragma unroll
    for (int mt = 0; mt < 3; ++mt)
        #pragma unroll
        for (int nt = 0; nt < 4; ++nt) Y[mt][nt] = (f32x4){0.f, 0.f, 0.f, 0.f};

    const unsigned short* obase = wt + (size_t)3 * WMAT + (w * 64 + lr) * D_DIM;
    #pragma unroll 2
    for (int ks = 0; ks < 16; ++ks) {
        bf16x8 afr[3];
        #pragma unroll
        for (int mt = 0; mt < 3; ++mt)
            afr[mt] = *(const bf16x8*)(Ast + xswc(mt * 16 + lr, ks * 32 + lg * 8));
        #pragma unroll
        for (int nt = 0; nt < 4; ++nt) {
            bf16x8 bfr = *(const bf16x8*)(obase + nt * 16 * D_DIM + ks * 32 + lg * 8);
            #pragma unroll
            for (int mt = 0; mt < 3; ++mt)
                Y[mt][nt] = __builtin_amdgcn_mfma_f32_16x16x32_bf16(afr[mt], bfr, Y[mt][nt], 0, 0, 0);
        }
    }

    // epilogue: +bo, +x (fp32), LayerNorm, store
    float bo4[4], gm4[4], bt4[4];
    int cols[4];
    #pragma unroll
    for (int nt = 0; nt < 4; ++nt) {
        cols[nt] = w * 64 + nt * 16 + lr;
        bo4[nt] = bo[cols[nt]]; gm4[nt] = gamma[cols[nt]]; bt4[nt] = beta[cols[nt]];
    }
    #pragma unroll
    for (int mt = 0; mt < 3; ++mt)
        #pragma unroll
        for (int j = 0; j < 4; ++j) {
            int rowl = mt * 16 + lg * 4 + j;
            const float* xrow = x + (row0 + rowl) * (size_t)D_DIM;
            float ps = 0.f, pq = 0.f;
            #pragma unroll
            for (int nt = 0; nt < 4; ++nt) {
                float y = Y[mt][nt][j] + bo4[nt] + xrow[cols[nt]];
                Y[mt][nt][j] = y;
                ps += y; pq += y * y;
            }
            ps += __shfl_xor(ps, 1); pq += __shfl_xor(pq, 1);
            ps += __shfl_xor(ps, 2); pq += __shfl_xor(pq, 2);
            ps += __shfl_xor(ps, 4); pq += __shfl_xor(pq, 4);
            ps += __shfl_xor(ps, 8); pq += __shfl_xor(pq, 8);
            if (lr == 0) { red[rowl * 17 + w * 2] = ps; red[rowl * 17 + w * 2 + 1] = pq; }
        }
    __syncthreads();
    if (tid < ROWS2) {
        float s = 0.f, q = 0.f;
        #pragma unroll
        for (int w8 = 0; w8 < 8; ++w8) { s += red[tid * 17 + w8 * 2]; q += red[tid * 17 + w8 * 2 + 1]; }
        float mu = s * (1.f / 512.f);
        float var = q * (1.f / 512.f) - mu * mu;
        musig[tid * 2] = mu;
        musig[tid * 2 + 1] = rsqrtf(var + 1e-5f);
    }
    __syncthreads();
    #pragma unroll
    for (int mt = 0; mt < 3; ++mt)
        #pragma unroll
        for (int j = 0; j < 4; ++j) {
            int rowl = mt * 16 + lg * 4 + j;
            float mu = musig[rowl * 2], rs = musig[rowl * 2 + 1];
            float* orow = out + (row0 + rowl) * (size_t)D_DIM;
            #pragma unroll
            for (int nt = 0; nt < 4; ++nt)
                orow[cols[nt]] = (Y[mt][nt][j] - mu) * rs * gm4[nt] + bt4[nt];
        }
}

extern "C" void kernel_launch(void* const* d_in, const int* in_sizes, int n_in,
                              void* d_out, int out_size, void* d_ws, size_t ws_size,
                              hipStream_t stream) {
    (void)in_sizes; (void)n_in; (void)out_size; (void)ws_size;
    const float* x     = (const float*)d_in[0];
    const float* Wq    = (const float*)d_in[1];
    const float* bq    = (const float*)d_in[2];
    const float* Wk    = (const float*)d_in[3];
    const float* bk    = (const float*)d_in[4];
    const float* Wv    = (const float*)d_in[5];
    const float* bv    = (const float*)d_in[6];
    const float* adj   = (const float*)d_in[7];
    const float* Wo    = (const float*)d_in[8];
    const float* bo    = (const float*)d_in[9];
    const float* gamma = (const float*)d_in[10];
    const float* beta  = (const float*)d_in[11];
    unsigned short* wt = (unsigned short*)d_ws;      // 4 * 512*512 bf16 = 2 MiB

    prep_weights<<<4096, 256, 0, stream>>>(Wq, Wk, Wv, Wo, wt);
    qkv_attn<<<16384 / G_B1, THREADS1, SMEM1, stream>>>(
        x, wt, bq, bk, bv, adj, (unsigned short*)d_out);
    oproj_ln<<<16384 / G_B2, THREADS2, SMEM2, stream>>>(
        x, wt, bo, gamma, beta, (float*)d_out);
}

// Round 14
// 1374.604 us; speedup vs baseline: 1.2787x; 1.0097x over previous
//
#include <hip/hip_runtime.h>
#include <hip/hip_bf16.h>

#define D_DIM 512
#define S_LEN 12
#define H_NUM 8
#define WMAT 262144       // 512*512

// ---- kernel1: G_B=4, 48 rows, 6 waves, 1-head groups, 2 col-tiles/wave ----
// LDS 71,424 B -> 2 blocks/CU -> 12 waves/CU in two independent barrier domains
#define G_B1 4
#define ROWS1 48          // 3 M-tiles of 16
#define THREADS1 384      // 6 waves
#define X_OFF   0         // [48][512] bf16 = 49152
#define QKV_OFF 49152     // 3 x [48][64] u16 (Q,K,V of current head) = 18432
#define TBLK    3072      // 48*64 u16 per tensor
#define P_OFF   67584     // 4 x [12][20] f32 = 3840
#define SMEM1   71424     // x2 = 142848 <= 163840 -> 2 blocks/CU

// ---- kernel2 (R13-proven): G_B=4, 512 threads, 2 blocks/CU; A read as bf16 ----
#define G_B2 4
#define ROWS2 48
#define THREADS2 512
#define AST_OFF 0         // [48][512] bf16 = 49152
#define RED_OFF 49152     // [48][17] f32 = 3264
#define MU_OFF  52416     // [48][2] f32 = 384
#define SMEM2   52800     // x2 -> 2 blocks/CU

// A intermediate: bf16, row r at u16-elem index r*1024 + c (low 1024 B of row r's
// 2048 B f32 slot in d_out). K2 block reads exactly the bytes it later overwrites.

typedef __attribute__((ext_vector_type(8))) short bf16x8;
typedef __attribute__((ext_vector_type(4))) float f32x4;

__device__ __forceinline__ unsigned short f2bf(float f) {
    union { float f; unsigned u; } c; c.f = f;
    unsigned r = c.u + 0x7fffu + ((c.u >> 16) & 1u);
    return (unsigned short)(r >> 16);
}
__device__ __forceinline__ float bf2f(unsigned short u) {
    union { unsigned u; float f; } c; c.u = ((unsigned)u) << 16;
    return c.f;
}
// 16B-granule XOR swizzle, 512-col tiles
__device__ __forceinline__ int xswc(int row, int col) {
    return row * 512 + (((col >> 3) ^ (row & 7)) << 3) + (col & 7);
}
// 64-col tiles, stride 64, 16B-chunk XOR
__device__ __forceinline__ int qsw64(int row, int col) {
    return row * 64 + (((col >> 3) ^ (row & 7)) << 3) + (col & 7);
}

__global__ void prep_weights(const float* __restrict__ Wq, const float* __restrict__ Wk,
                             const float* __restrict__ Wv, const float* __restrict__ Wo,
                             unsigned short* __restrict__ wt) {
    int idx = blockIdx.x * 256 + threadIdx.x;   // 0 .. 4*WMAT-1
    int mat = idx >> 18;
    int rem = idx & (WMAT - 1);
    int e = rem >> 9, d = rem & 511;
    const float* W = (mat == 0) ? Wq : (mat == 1) ? Wk : (mat == 2) ? Wv : Wo;
    wt[idx] = f2bf(W[d * D_DIM + e]);           // wt[mat][e][d] = W[d][e]
}

// ---------------- kernel 1: QKV + attention -> A (bf16, packed into d_out) ----------------
__global__ __launch_bounds__(THREADS1, 3) void qkv_attn(
    const float* __restrict__ x, const unsigned short* __restrict__ wt,
    const float* __restrict__ bq, const float* __restrict__ bk, const float* __restrict__ bv,
    const float* __restrict__ adj, unsigned short* __restrict__ aout)
{
    extern __shared__ char smem[];
    unsigned short* Xh  = (unsigned short*)(smem + X_OFF);
    unsigned short* QKV = (unsigned short*)(smem + QKV_OFF);  // Q,K,V of current head
    float* Pl = (float*)(smem + P_OFF);         // [4][12][20]

    const int tid  = threadIdx.x;
    const int lane = tid & 63;
    const int w    = tid >> 6;          // wave 0..5
    const int lr   = lane & 15;
    const int lg   = lane >> 4;
    const int lr12 = (lr < 12) ? lr : 11;       // true clamp
    const size_t row0 = (size_t)blockIdx.x * ROWS1;

    // stage X -> LDS bf16 (swizzled): 6144 chunks of 4 f32, 16/thread
    #pragma unroll
    for (int it = 0; it < 16; ++it) {
        int idx = it * THREADS1 + tid;
        int r = idx >> 7, col = (idx & 127) << 2;
        float4 v = *(const float4*)(x + (row0 + r) * (size_t)D_DIM + col);
        ushort4 pk;
        pk.x = f2bf(v.x); pk.y = f2bf(v.y); pk.z = f2bf(v.z); pk.w = f2bf(v.w);
        *(ushort4*)(Xh + xswc(r, col)) = pk;
    }
    __syncthreads();

    // per-head col-space [mat(3)][col(64)] = 192 cols = 12 tiles; wave owns 2:
    // cols [32w, 32w+32) -> tile ct: mat = colglob>>6, c0 = colglob&63
    int matn[2], c0n[2];
    #pragma unroll
    for (int ct = 0; ct < 2; ++ct) {
        int colglob = w * 32 + ct * 16;
        matn[ct] = colglob >> 6;
        c0n[ct]  = colglob & 63;
    }
    // attention: 4 tasks (batch items), waves 0-3
    const int rbA = w * S_LEN;

    #pragma unroll 1
    for (int h = 0; h < H_NUM; ++h) {
        // ---------------- QKV projection for head h ----------------
        f32x4 acc[3][2];                // [mt][ct]
        #pragma unroll
        for (int mt = 0; mt < 3; ++mt)
            #pragma unroll
            for (int ct = 0; ct < 2; ++ct) acc[mt][ct] = (f32x4){0.f, 0.f, 0.f, 0.f};

        const unsigned short* bp0 = wt + (size_t)matn[0] * WMAT + (h * 64 + c0n[0] + lr) * D_DIM + lg * 8;
        const unsigned short* bp1 = wt + (size_t)matn[1] * WMAT + (h * 64 + c0n[1] + lr) * D_DIM + lg * 8;

        #pragma unroll
        for (int ks = 0; ks < 16; ++ks) {
            bf16x8 b0 = *(const bf16x8*)(bp0 + ks * 32);
            bf16x8 b1 = *(const bf16x8*)(bp1 + ks * 32);
            bf16x8 af[3];
            #pragma unroll
            for (int mt = 0; mt < 3; ++mt)
                af[mt] = *(const bf16x8*)(Xh + xswc(mt * 16 + lr, ks * 32 + lg * 8));
            #pragma unroll
            for (int mt = 0; mt < 3; ++mt) {
                acc[mt][0] = __builtin_amdgcn_mfma_f32_16x16x32_bf16(af[mt], b0, acc[mt][0], 0, 0, 0);
                acc[mt][1] = __builtin_amdgcn_mfma_f32_16x16x32_bf16(af[mt], b1, acc[mt][1], 0, 0, 0);
            }
        }
        // store Q/K/V (+bias)
        #pragma unroll
        for (int ct = 0; ct < 2; ++ct) {
            int mat = matn[ct];
            unsigned short* T = QKV + mat * TBLK;
            const float* bsel = (mat == 0) ? bq : (mat == 1) ? bk : bv;
            float bias = bsel[h * 64 + c0n[ct] + lr];
            #pragma unroll
            for (int mt = 0; mt < 3; ++mt)
                #pragma unroll
                for (int j = 0; j < 4; ++j)
                    T[qsw64(mt * 16 + lg * 4 + j, c0n[ct] + lr)] = f2bf(acc[mt][ct][j] + bias);
        }
        __syncthreads();   // Q/K/V of head h visible

        // ---------------- attention: waves 0-3 <-> batch items 0-3 ----------------
        if (w < 4) {
            const unsigned short* Qb = QKV;
            const unsigned short* Kb = QKV + TBLK;
            const unsigned short* Vb = QKV + 2 * TBLK;

            f32x4 sacc = (f32x4){0.f, 0.f, 0.f, 0.f};
            #pragma unroll
            for (int k2 = 0; k2 < 2; ++k2) {
                bf16x8 ak = *(const bf16x8*)(Kb + qsw64(rbA + lr12, k2 * 32 + lg * 8));
                bf16x8 aq = *(const bf16x8*)(Qb + qsw64(rbA + lr12, k2 * 32 + lg * 8));
                sacc = __builtin_amdgcn_mfma_f32_16x16x32_bf16(ak, aq, sacc, 0, 0, 0);
            }
            float ab4[4] = {0.f, 0.f, 0.f, 0.f};
            if (lg < 3 && lr < 12) {
                float4 t4 = *(const float4*)(adj + (h * S_LEN + lr) * S_LEN + lg * 4);
                ab4[0] = t4.x; ab4[1] = t4.y; ab4[2] = t4.z; ab4[3] = t4.w;
            }
            float sc[4], e4[4];
            float m = -1e30f;
            #pragma unroll
            for (int j = 0; j < 4; ++j) {
                int tt = lg * 4 + j;
                sc[j] = (tt < 12) ? (sacc[j] * 0.125f + ab4[j]) : -1e30f;
                m = fmaxf(m, sc[j]);
            }
            m = fmaxf(m, __shfl_xor(m, 16));
            m = fmaxf(m, __shfl_xor(m, 32));
            float ssum = 0.f;
            #pragma unroll
            for (int j = 0; j < 4; ++j) { e4[j] = __expf(sc[j] - m); ssum += e4[j]; }
            ssum += __shfl_xor(ssum, 16);
            ssum += __shfl_xor(ssum, 32);
            float inv = 1.f / ssum;
            float* Pw = Pl + w * 240;
            if (lr < 12 && lg < 3) {
                f32x4 pvec = (f32x4){e4[0] * inv, e4[1] * inv, e4[2] * inv, e4[3] * inv};
                *(f32x4*)(Pw + lr * 20 + lg * 4) = pvec;
            }
            // same-wave P write -> read: no barrier needed (validated R5-R13)
            float vv[12];
            #pragma unroll
            for (int t2 = 0; t2 < 12; ++t2) vv[t2] = bf2f(Vb[qsw64(rbA + t2, lane)]);
            #pragma unroll
            for (int ss = 0; ss < 12; ++ss) {
                f32x4 pa = *(const f32x4*)(Pw + ss * 20);
                f32x4 pb = *(const f32x4*)(Pw + ss * 20 + 4);
                f32x4 pc = *(const f32x4*)(Pw + ss * 20 + 8);
                float o = 0.f;
                #pragma unroll
                for (int t2 = 0; t2 < 4; ++t2) o += pa[t2] * vv[t2];
                #pragma unroll
                for (int t2 = 0; t2 < 4; ++t2) o += pb[t2] * vv[4 + t2];
                #pragma unroll
                for (int t2 = 0; t2 < 4; ++t2) o += pc[t2] * vv[8 + t2];
                // bf16 A, packed: row r's data at u16-elem r*1024 + col
                aout[(row0 + rbA + ss) * 1024 + h * 64 + lane] = f2bf(o);
            }
        }
        if (h < H_NUM - 1) __syncthreads();  // attention reads done before next head's stores
    }
}

// ---------------- kernel 2: out-proj + bias + residual + LayerNorm (in-place) ----------------
__global__ __launch_bounds__(THREADS2, 2) void oproj_ln(
    const float* __restrict__ x, const unsigned short* __restrict__ wt,
    const float* __restrict__ bo, const float* __restrict__ gamma,
    const float* __restrict__ beta, float* __restrict__ out)
{
    extern __shared__ char smem[];
    unsigned short* Ast = (unsigned short*)(smem + AST_OFF);  // [48][512] bf16
    float* red   = (float*)(smem + RED_OFF);   // [48][17]
    float* musig = (float*)(smem + MU_OFF);    // [48][2]

    const int tid  = threadIdx.x;
    const int lane = tid & 63;
    const int w    = tid >> 6;
    const int lr   = lane & 15;
    const int lg   = lane >> 4;
    const size_t row0 = (size_t)blockIdx.x * ROWS2;
    const unsigned short* abase = (const unsigned short*)out;  // bf16 A region

    // stage A (bf16, low half of each row's f32 slot) -> LDS, straight 16B copy.
    #pragma unroll
    for (int it = 0; it < 6; ++it) {
        int idx = it * THREADS2 + tid;
        int r = idx >> 6, c8 = (idx & 63) << 3;
        uint4 v = *(const uint4*)(abase + (row0 + r) * 1024 + c8);
        *(uint4*)(Ast + xswc(r, c8)) = v;
    }
    __syncthreads();

    f32x4 Y[3][4];
    #pragma unroll
    for (int mt = 0; mt < 3; ++mt)
        #pragma unroll
        for (int nt = 0; nt < 4; ++nt) Y[mt][nt] = (f32x4){0.f, 0.f, 0.f, 0.f};

    const unsigned short* obase = wt + (size_t)3 * WMAT + (w * 64 + lr) * D_DIM;
    #pragma unroll 2
    for (int ks = 0; ks < 16; ++ks) {
        bf16x8 afr[3];
        #pragma unroll
        for (int mt = 0; mt < 3; ++mt)
            afr[mt] = *(const bf16x8*)(Ast + xswc(mt * 16 + lr, ks * 32 + lg * 8));
        #pragma unroll
        for (int nt = 0; nt < 4; ++nt) {
            bf16x8 bfr = *(const bf16x8*)(obase + nt * 16 * D_DIM + ks * 32 + lg * 8);
            #pragma unroll
            for (int mt = 0; mt < 3; ++mt)
                Y[mt][nt] = __builtin_amdgcn_mfma_f32_16x16x32_bf16(afr[mt], bfr, Y[mt][nt], 0, 0, 0);
        }
    }

    // epilogue: +bo, +x (fp32), LayerNorm, store
    float bo4[4], gm4[4], bt4[4];
    int cols[4];
    #pragma unroll
    for (int nt = 0; nt < 4; ++nt) {
        cols[nt] = w * 64 + nt * 16 + lr;
        bo4[nt] = bo[cols[nt]]; gm4[nt] = gamma[cols[nt]]; bt4[nt] = beta[cols[nt]];
    }
    #pragma unroll
    for (int mt = 0; mt < 3; ++mt)
        #pragma unroll
        for (int j = 0; j < 4; ++j) {
            int rowl = mt * 16 + lg * 4 + j;
            const float* xrow = x + (row0 + rowl) * (size_t)D_DIM;
            float ps = 0.f, pq = 0.f;
            #pragma unroll
            for (int nt = 0; nt < 4; ++nt) {
                float y = Y[mt][nt][j] + bo4[nt] + xrow[cols[nt]];
                Y[mt][nt][j] = y;
                ps += y; pq += y * y;
            }
            ps += __shfl_xor(ps, 1); pq += __shfl_xor(pq, 1);
            ps += __shfl_xor(ps, 2); pq += __shfl_xor(pq, 2);
            ps += __shfl_xor(ps, 4); pq += __shfl_xor(pq, 4);
            ps += __shfl_xor(ps, 8); pq += __shfl_xor(pq, 8);
            if (lr == 0) { red[rowl * 17 + w * 2] = ps; red[rowl * 17 + w * 2 + 1] = pq; }
        }
    __syncthreads();
    if (tid < ROWS2) {
        float s = 0.f, q = 0.f;
        #pragma unroll
        for (int w8 = 0; w8 < 8; ++w8) { s += red[tid * 17 + w8 * 2]; q += red[tid * 17 + w8 * 2 + 1]; }
        float mu = s * (1.f / 512.f);
        float var = q * (1.f / 512.f) - mu * mu;
        musig[tid * 2] = mu;
        musig[tid * 2 + 1] = rsqrtf(var + 1e-5f);
    }
    __syncthreads();
    #pragma unroll
    for (int mt = 0; mt < 3; ++mt)
        #pragma unroll
        for (int j = 0; j < 4; ++j) {
            int rowl = mt * 16 + lg * 4 + j;
            float mu = musig[rowl * 2], rs = musig[rowl * 2 + 1];
            float* orow = out + (row0 + rowl) * (size_t)D_DIM;
            #pragma unroll
            for (int nt = 0; nt < 4; ++nt)
                orow[cols[nt]] = (Y[mt][nt][j] - mu) * rs * gm4[nt] + bt4[nt];
        }
}

extern "C" void kernel_launch(void* const* d_in, const int* in_sizes, int n_in,
                              void* d_out, int out_size, void* d_ws, size_t ws_size,
                              hipStream_t stream) {
    (void)in_sizes; (void)n_in; (void)out_size; (void)ws_size;
    const float* x     = (const float*)d_in[0];
    const float* Wq    = (const float*)d_in[1];
    const float* bq    = (const float*)d_in[2];
    const float* Wk    = (const float*)d_in[3];
    const float* bk    = (const float*)d_in[4];
    const float* Wv    = (const float*)d_in[5];
    const float* bv    = (const float*)d_in[6];
    const float* adj   = (const float*)d_in[7];
    const float* Wo    = (const float*)d_in[8];
    const float* bo    = (const float*)d_in[9];
    const float* gamma = (const float*)d_in[10];
    const float* beta  = (const float*)d_in[11];
    unsigned short* wt = (unsigned short*)d_ws;      // 4 * 512*512 bf16 = 2 MiB

    prep_weights<<<4096, 256, 0, stream>>>(Wq, Wk, Wv, Wo, wt);
    qkv_attn<<<16384 / G_B1, THREADS1, SMEM1, stream>>>(
        x, wt, bq, bk, bv, adj, (unsigned short*)d_out);
    oproj_ln<<<16384 / G_B2, THREADS2, SMEM2, stream>>>(
        x, wt, bo, gamma, beta, (float*)d_out);
}

// Round 15
// 943.459 us; speedup vs baseline: 1.8630x; 1.4570x over previous
//
#include <hip/hip_runtime.h>
#include <hip/hip_bf16.h>

#define D_DIM 512
#define S_LEN 12
#define H_NUM 8
#define WMAT 262144       // 512*512

// ---- kernel1 (R8-proven): G_B=8, 96 rows, 12 waves ----
#define G_B1 8
#define ROWS1 96          // 6 M-tiles
#define THREADS1 768      // 12 waves: wave = (mat, colt)
#define X_OFF   0         // [96][512] bf16 = 98304
#define Q_OFF   98304     // [96][64] bf16 = 12288
#define K_OFF   110592
#define V_OFF   122880
#define P_OFF   135168    // 8 x [12][20] f32 = 7680
#define SMEM1   142848    // 1 block/CU

// ---- kernel2: G_B=8, 512 threads, Y[6][4] (R1-proven acc footprint) ----
#define G_B2 8
#define ROWS2 96
#define THREADS2 512
#define AST_OFF 0         // [96][512] bf16 = 98304
#define RED_OFF 98304     // [96][17] f32 = 6528
#define MU_OFF  104832    // [96][2] f32 = 768
#define SMEM2   105600    // 1 block/CU

// A intermediate: bf16, row r at u16-elem index r*1024 + c (low 1024 B of row r's
// 2048 B f32 slot in d_out). K2 block reads exactly the bytes it later overwrites.

typedef __attribute__((ext_vector_type(8))) short bf16x8;
typedef __attribute__((ext_vector_type(4))) float f32x4;

__device__ __forceinline__ unsigned short f2bf(float f) {
    union { float f; unsigned u; } c; c.f = f;
    unsigned r = c.u + 0x7fffu + ((c.u >> 16) & 1u);
    return (unsigned short)(r >> 16);
}
__device__ __forceinline__ float bf2f(unsigned short u) {
    union { unsigned u; float f; } c; c.u = ((unsigned)u) << 16;
    return c.f;
}
// 16B-granule XOR swizzle, 512-col tiles
__device__ __forceinline__ int xswc(int row, int col) {
    return row * 512 + (((col >> 3) ^ (row & 7)) << 3) + (col & 7);
}
// 64-col tiles, stride 64, 16B-chunk XOR
__device__ __forceinline__ int qsw(int row, int col) {
    return row * 64 + (((col >> 3) ^ (row & 7)) << 3) + (col & 7);
}

__global__ void prep_weights(const float* __restrict__ Wq, const float* __restrict__ Wk,
                             const float* __restrict__ Wv, const float* __restrict__ Wo,
                             unsigned short* __restrict__ wt) {
    int idx = blockIdx.x * 256 + threadIdx.x;   // 0 .. 4*WMAT-1
    int mat = idx >> 18;
    int rem = idx & (WMAT - 1);
    int e = rem >> 9, d = rem & 511;
    const float* W = (mat == 0) ? Wq : (mat == 1) ? Wk : (mat == 2) ? Wv : Wo;
    wt[idx] = f2bf(W[d * D_DIM + e]);           // wt[mat][e][d] = W[d][e]
}

// ---------------- kernel 1: QKV + attention -> A (bf16, packed into d_out) ----------------
__global__ __launch_bounds__(THREADS1, 3) void qkv_attn(
    const float* __restrict__ x, const unsigned short* __restrict__ wt,
    const float* __restrict__ bq, const float* __restrict__ bk, const float* __restrict__ bv,
    const float* __restrict__ adj, unsigned short* __restrict__ aout)
{
    extern __shared__ char smem[];
    unsigned short* Xh = (unsigned short*)(smem + X_OFF);
    unsigned short* Qh = (unsigned short*)(smem + Q_OFF);
    unsigned short* Kh = (unsigned short*)(smem + K_OFF);
    unsigned short* Vh = (unsigned short*)(smem + V_OFF);
    float* Pl = (float*)(smem + P_OFF);         // [8][12][20]

    const int tid  = threadIdx.x;
    const int lane = tid & 63;
    const int w    = tid >> 6;          // wave 0..11
    const int lr   = lane & 15;
    const int lg   = lane >> 4;
    const int lr12 = (lr < 12) ? lr : 11;       // true clamp
    const size_t row0 = (size_t)blockIdx.x * ROWS1;

    // stage X -> LDS bf16 (swizzled): 12288 float4 chunks, 16 per thread
    #pragma unroll
    for (int it = 0; it < 16; ++it) {
        int idx = it * THREADS1 + tid;
        int r = idx >> 7, col = (idx & 127) << 2;
        float4 v = *(const float4*)(x + (row0 + r) * (size_t)D_DIM + col);
        ushort4 pk;
        pk.x = f2bf(v.x); pk.y = f2bf(v.y); pk.z = f2bf(v.z); pk.w = f2bf(v.w);
        *(ushort4*)(Xh + xswc(r, col)) = pk;
    }
    __syncthreads();

    // wave task: mat = w>>2 (0=Q,1=K,2=V), colt = w&3; owns all 6 M-tiles.
    const int mat  = w >> 2;
    const int colt = w & 3;
    const int colh = colt * 16 + lr;
    const float* bsel = (mat == 0) ? bq : (mat == 1) ? bk : bv;
    unsigned short* T = (mat == 0) ? Qh : (mat == 1) ? Kh : Vh;
    const int rb = w * S_LEN;                   // attention rows (waves 0-7)

    #pragma unroll 1
    for (int h = 0; h < H_NUM; ++h) {
        // ---------------- QKV projection for head h ----------------
        f32x4 acc[6];
        #pragma unroll
        for (int mt = 0; mt < 6; ++mt) acc[mt] = (f32x4){0.f, 0.f, 0.f, 0.f};

        const unsigned short* bAp = wt + (size_t)mat * WMAT + (h * 64 + colh) * D_DIM + lg * 8;
        bf16x8 bc = *(const bf16x8*)(bAp);      // B double-buffer: preload ks=0
        #pragma unroll
        for (int ks = 0; ks < 16; ++ks) {
            bf16x8 bn;
            if (ks < 15) bn = *(const bf16x8*)(bAp + (ks + 1) * 32);   // prefetch next
            #pragma unroll
            for (int mt = 0; mt < 6; ++mt) {
                bf16x8 af = *(const bf16x8*)(Xh + xswc(mt * 16 + lr, ks * 32 + lg * 8));
                acc[mt] = __builtin_amdgcn_mfma_f32_16x16x32_bf16(af, bc, acc[mt], 0, 0, 0);
            }
            if (ks < 15) bc = bn;
        }
        {
            float bias = bsel[h * 64 + colh];
            #pragma unroll
            for (int mt = 0; mt < 6; ++mt)
                #pragma unroll
                for (int j = 0; j < 4; ++j)
                    T[qsw(mt * 16 + lg * 4 + j, colh)] = f2bf(acc[mt][j] + bias);
        }
        __syncthreads();   // Q/K/V complete

        // ---------------- attention (waves 0-7 <-> batch items 0-7) ----------------
        if (w < 8) {
            f32x4 sacc = (f32x4){0.f, 0.f, 0.f, 0.f};
            #pragma unroll
            for (int k2 = 0; k2 < 2; ++k2) {
                bf16x8 ak = *(const bf16x8*)(Kh + qsw(rb + lr12, k2 * 32 + lg * 8));
                bf16x8 aq = *(const bf16x8*)(Qh + qsw(rb + lr12, k2 * 32 + lg * 8));
                sacc = __builtin_amdgcn_mfma_f32_16x16x32_bf16(ak, aq, sacc, 0, 0, 0);
            }
            float ab4[4] = {0.f, 0.f, 0.f, 0.f};
            if (lg < 3 && lr < 12) {
                float4 t4 = *(const float4*)(adj + (h * S_LEN + lr) * S_LEN + lg * 4);
                ab4[0] = t4.x; ab4[1] = t4.y; ab4[2] = t4.z; ab4[3] = t4.w;
            }
            float sc[4], e4[4];
            float m = -1e30f;
            #pragma unroll
            for (int j = 0; j < 4; ++j) {
                int t = lg * 4 + j;
                sc[j] = (t < 12) ? (sacc[j] * 0.125f + ab4[j]) : -1e30f;
                m = fmaxf(m, sc[j]);
            }
            m = fmaxf(m, __shfl_xor(m, 16));
            m = fmaxf(m, __shfl_xor(m, 32));
            float ssum = 0.f;
            #pragma unroll
            for (int j = 0; j < 4; ++j) { e4[j] = __expf(sc[j] - m); ssum += e4[j]; }
            ssum += __shfl_xor(ssum, 16);
            ssum += __shfl_xor(ssum, 32);
            float inv = 1.f / ssum;
            float* Pw = Pl + w * 240;
            if (lr < 12 && lg < 3) {
                f32x4 pvec = (f32x4){e4[0] * inv, e4[1] * inv, e4[2] * inv, e4[3] * inv};
                *(f32x4*)(Pw + lr * 20 + lg * 4) = pvec;
            }
            // same-wave P write -> read: no barrier needed (validated R5-R14)
            float vv[12];
            #pragma unroll
            for (int t = 0; t < 12; ++t) vv[t] = bf2f(Vh[qsw(rb + t, lane)]);
            #pragma unroll
            for (int ss = 0; ss < 12; ++ss) {
                f32x4 pa = *(const f32x4*)(Pw + ss * 20);
                f32x4 pb = *(const f32x4*)(Pw + ss * 20 + 4);
                f32x4 pc = *(const f32x4*)(Pw + ss * 20 + 8);
                float o = 0.f;
                #pragma unroll
                for (int t = 0; t < 4; ++t) o += pa[t] * vv[t];
                #pragma unroll
                for (int t = 0; t < 4; ++t) o += pb[t] * vv[4 + t];
                #pragma unroll
                for (int t = 0; t < 4; ++t) o += pc[t] * vv[8 + t];
                // bf16 A, packed: row r's data at u16-elem r*1024 + col
                aout[(row0 + rb + ss) * 1024 + h * 64 + lane] = f2bf(o);
            }
        }
        __syncthreads();   // A consumers done; safe to overwrite Q/K/V next head
    }
}

// ---------------- kernel 2: out-proj + bias + residual + LayerNorm (in-place) ----------------
__global__ __launch_bounds__(THREADS2, 2) void oproj_ln(
    const float* __restrict__ x, const unsigned short* __restrict__ wt,
    const float* __restrict__ bo, const float* __restrict__ gamma,
    const float* __restrict__ beta, float* __restrict__ out)
{
    extern __shared__ char smem[];
    unsigned short* Ast = (unsigned short*)(smem + AST_OFF);  // [96][512] bf16
    float* red   = (float*)(smem + RED_OFF);   // [96][17]
    float* musig = (float*)(smem + MU_OFF);    // [96][2]

    const int tid  = threadIdx.x;
    const int lane = tid & 63;
    const int w    = tid >> 6;          // wave 0..7, cols [w*64, w*64+64)
    const int lr   = lane & 15;
    const int lg   = lane >> 4;
    const size_t row0 = (size_t)blockIdx.x * ROWS2;
    const unsigned short* abase = (const unsigned short*)out;  // bf16 A region

    // stage A (bf16, low half of each row's f32 slot) -> LDS, straight 16B copy.
    // 6144 chunks of 8 u16, 12/thread. In-place safe: reads precede the barrier,
    // and this block's f32 writes cover exactly these rows.
    #pragma unroll
    for (int it = 0; it < 12; ++it) {
        int idx = it * THREADS2 + tid;
        int r = idx >> 6, c8 = (idx & 63) << 3;
        uint4 v = *(const uint4*)(abase + (row0 + r) * 1024 + c8);
        *(uint4*)(Ast + xswc(r, c8)) = v;
    }
    __syncthreads();

    f32x4 Y[6][4];
    #pragma unroll
    for (int mt = 0; mt < 6; ++mt)
        #pragma unroll
        for (int nt = 0; nt < 4; ++nt) Y[mt][nt] = (f32x4){0.f, 0.f, 0.f, 0.f};

    const unsigned short* obase = wt + (size_t)3 * WMAT + (w * 64 + lr) * D_DIM;
    #pragma unroll 1
    for (int ks = 0; ks < 16; ++ks) {
        bf16x8 afr[6];
        #pragma unroll
        for (int mt = 0; mt < 6; ++mt)
            afr[mt] = *(const bf16x8*)(Ast + xswc(mt * 16 + lr, ks * 32 + lg * 8));
        #pragma unroll
        for (int nt = 0; nt < 4; ++nt) {
            bf16x8 bfr = *(const bf16x8*)(obase + nt * 16 * D_DIM + ks * 32 + lg * 8);
            #pragma unroll
            for (int mt = 0; mt < 6; ++mt)
                Y[mt][nt] = __builtin_amdgcn_mfma_f32_16x16x32_bf16(afr[mt], bfr, Y[mt][nt], 0, 0, 0);
        }
    }

    // epilogue: +bo, +x (fp32), LayerNorm, store
    float bo4[4], gm4[4], bt4[4];
    int cols[4];
    #pragma unroll
    for (int nt = 0; nt < 4; ++nt) {
        cols[nt] = w * 64 + nt * 16 + lr;
        bo4[nt] = bo[cols[nt]]; gm4[nt] = gamma[cols[nt]]; bt4[nt] = beta[cols[nt]];
    }
    #pragma unroll
    for (int mt = 0; mt < 6; ++mt)
        #pragma unroll
        for (int j = 0; j < 4; ++j) {
            int rowl = mt * 16 + lg * 4 + j;
            const float* xrow = x + (row0 + rowl) * (size_t)D_DIM;
            float ps = 0.f, pq = 0.f;
            #pragma unroll
            for (int nt = 0; nt < 4; ++nt) {
                float y = Y[mt][nt][j] + bo4[nt] + xrow[cols[nt]];
                Y[mt][nt][j] = y;
                ps += y; pq += y * y;
            }
            ps += __shfl_xor(ps, 1); pq += __shfl_xor(pq, 1);
            ps += __shfl_xor(ps, 2); pq += __shfl_xor(pq, 2);
            ps += __shfl_xor(ps, 4); pq += __shfl_xor(pq, 4);
            ps += __shfl_xor(ps, 8); pq += __shfl_xor(pq, 8);
            if (lr == 0) { red[rowl * 17 + w * 2] = ps; red[rowl * 17 + w * 2 + 1] = pq; }
        }
    __syncthreads();
    if (tid < ROWS2) {
        float s = 0.f, q = 0.f;
        #pragma unroll
        for (int w8 = 0; w8 < 8; ++w8) { s += red[tid * 17 + w8 * 2]; q += red[tid * 17 + w8 * 2 + 1]; }
        float mu = s * (1.f / 512.f);
        float var = q * (1.f / 512.f) - mu * mu;
        musig[tid * 2] = mu;
        musig[tid * 2 + 1] = rsqrtf(var + 1e-5f);
    }
    __syncthreads();
    #pragma unroll
    for (int mt = 0; mt < 6; ++mt)
        #pragma unroll
        for (int j = 0; j < 4; ++j) {
            int rowl = mt * 16 + lg * 4 + j;
            float mu = musig[rowl * 2], rs = musig[rowl * 2 + 1];
            float* orow = out + (row0 + rowl) * (size_t)D_DIM;
            #pragma unroll
            for (int nt = 0; nt < 4; ++nt)
                orow[cols[nt]] = (Y[mt][nt][j] - mu) * rs * gm4[nt] + bt4[nt];
        }
}

extern "C" void kernel_launch(void* const* d_in, const int* in_sizes, int n_in,
                              void* d_out, int out_size, void* d_ws, size_t ws_size,
                              hipStream_t stream) {
    (void)in_sizes; (void)n_in; (void)out_size; (void)ws_size;
    const float* x     = (const float*)d_in[0];
    const float* Wq    = (const float*)d_in[1];
    const float* bq    = (const float*)d_in[2];
    const float* Wk    = (const float*)d_in[3];
    const float* bk    = (const float*)d_in[4];
    const float* Wv    = (const float*)d_in[5];
    const float* bv    = (const float*)d_in[6];
    const float* adj   = (const float*)d_in[7];
    const float* Wo    = (const float*)d_in[8];
    const float* bo    = (const float*)d_in[9];
    const float* gamma = (const float*)d_in[10];
    const float* beta  = (const float*)d_in[11];
    unsigned short* wt = (unsigned short*)d_ws;      // 4 * 512*512 bf16 = 2 MiB

    prep_weights<<<4096, 256, 0, stream>>>(Wq, Wk, Wv, Wo, wt);
    qkv_attn<<<16384 / G_B1, THREADS1, SMEM1, stream>>>(
        x, wt, bq, bk, bv, adj, (unsigned short*)d_out);
    oproj_ln<<<16384 / G_B2, THREADS2, SMEM2, stream>>>(
        x, wt, bo, gamma, beta, (float*)d_out);
}